// Round 19
// baseline (2430.845 us; speedup 1.0000x reference)
//
#include <hip/hip_runtime.h>
#include <hip/hip_bf16.h>

__device__ __forceinline__ float elu1(float v) { return v > 0.f ? v : expm1f(v); }

// ---------------- cnorm: ||cb_k||^2 per code ----------------
__global__ void cnorm_kernel(const float* __restrict__ cb, float* __restrict__ cnorm) {
    int g = blockIdx.x * blockDim.x + threadIdx.x;  // 0..8191  (q*1024+k)
    if (g >= 8 * 1024) return;
    const float* p = cb + (size_t)g * 256;
    float s = 0.f;
    for (int d = 0; d < 256; d += 4) {
        float4 v = *reinterpret_cast<const float4*>(p + d);
        s += v.x * v.x + v.y * v.y + v.z * v.z + v.w * v.w;
    }
    cnorm[g] = s;
}

// ---------------- cbtrans: codebook -> stage-major layout -------------------
__global__ void cbtrans_kernel(const float* __restrict__ cb, float* __restrict__ cbT) {
    int t = blockIdx.x * blockDim.x + threadIdx.x;  // 0..524287 (float4 units)
    int o = t * 4;
    const int s = o >> 13;
    const int r = o & 8191;
    const int dl = r >> 10;
    const int k = r & 1023;
    const int q = s >> 5;
    const int d = (s & 31) * 8 + dl;
    const float* src = cb + ((size_t)(q * 1024 + k)) * 256 + d;
    float4 v;
    v.x = src[0 * 256]; v.y = src[1 * 256]; v.z = src[2 * 256]; v.w = src[3 * 256];
    *reinterpret_cast<float4*>(cbT + o) = v;
}

// ------------- wtrans v2: LANE-DENSE transposed weight layouts --------------
__global__ void wtrans_kernel(const float* __restrict__ W1, const float* __restrict__ W2,
                              const float* __restrict__ W3, float* __restrict__ W1c,
                              float* __restrict__ W2c, float* __restrict__ W3c) {
    int g = blockIdx.x * blockDim.x + threadIdx.x;
    if (g < 16384) {  // W1c, float4 units
        int ci = g >> 8, io = (g >> 6) & 3, cg = g & 63;
        int c = cg + (io >> 1) * 64;
        const float* src = W1 + c * 512 + ci * 8 + (io & 1) * 4;
        *reinterpret_cast<float4*>(W1c + g * 4) =
            *reinterpret_cast<const float4*>(src);
    }
    int g2 = g - 16384;
    if (g2 >= 0 && g2 < 98304) {  // W2c, float4 units
        int ci = g2 / 768, rem = g2 % 768;
        int jq = rem >> 8, c = rem & 255;
        float v[4];
#pragma unroll
        for (int e = 0; e < 4; ++e) {
            int j = jq * 4 + e;
            v[e] = (j < 10) ? W2[c * 1280 + ci * 10 + j] : 0.f;
        }
        float4 o; o.x = v[0]; o.y = v[1]; o.z = v[2]; o.w = v[3];
        *reinterpret_cast<float4*>(W2c + g2 * 4) = o;
    }
    int g3 = g - 16384 - 98304;
    if (g3 >= 0 && g3 < 196608) {  // W3c, float2 units
        int ci = g3 / 768, rem = g3 % 768;
        int jq = rem >> 8, c = rem & 255;
        const float* src = W3 + c * 3072 + ci * 12 + 6 + jq * 2;
        W3c[g3 * 2] = src[0];
        W3c[g3 * 2 + 1] = src[1];
    }
}

// ================= convA v3 (r16 body) + lane-dense W1c loads ================
__global__ __launch_bounds__(256, 2)
void convA_kernel(const float* __restrict__ audio,
                  const float* __restrict__ W0, const float* __restrict__ b0,
                  const float* __restrict__ W1c, const float* __restrict__ b1,
                  float* __restrict__ y1g) {
    __shared__ __align__(16) float xs[244];
    __shared__ __align__(16) float y0s[2 * 64 * 124];  // 62KB, 4 left pad cols

    const int tid = threadIdx.x;
    const int bbase = blockIdx.x * 2;

    if (tid < 128) {
        const int bz = tid >> 6, ciz = tid & 63;
        float* p = y0s + (bz * 64 + ciz) * 124;
        p[0] = 0.f; p[1] = 0.f; p[2] = 0.f; p[3] = 0.f;
    }

    for (int bi2 = 0; bi2 < 2; ++bi2) {
        __syncthreads();
        if (tid < 242) xs[tid] = (tid < 2) ? 0.f : audio[(bbase + bi2) * 240 + tid - 2];
        __syncthreads();
        const int ci = tid >> 2, tg = tid & 3;
        float4 w = *reinterpret_cast<const float4*>(W0 + ci * 4);
        float bias = b0[ci];
        for (int t = tg; t < 120; t += 4) {
            float v = bias + w.x * xs[2 * t] + w.y * xs[2 * t + 1]
                           + w.z * xs[2 * t + 2] + w.w * xs[2 * t + 3];
            y0s[(bi2 * 64 + ci) * 124 + 4 + t] = elu1(v);
        }
    }
    __syncthreads();
    {
        const int bi = tid >> 7;
        const int half = (tid >> 6) & 1;
        const int cg = tid & 63;
        const int t0 = 15 * half;
        float acc0[15], acc1[15];
        const float bias0 = b1[cg], bias1 = b1[cg + 64];
#pragma unroll
        for (int u = 0; u < 15; ++u) { acc0[u] = bias0; acc1[u] = bias1; }
        const float* w1base = W1c + cg * 4;
        const float* ybase = y0s + bi * 64 * 124 + 4 * t0;
        for (int ci = 0; ci < 64; ++ci) {
            float4 wA0 = *reinterpret_cast<const float4*>(w1base + (ci * 4 + 0) * 256);
            float4 wB0 = *reinterpret_cast<const float4*>(w1base + (ci * 4 + 1) * 256);
            float4 wA1 = *reinterpret_cast<const float4*>(w1base + (ci * 4 + 2) * 256);
            float4 wB1 = *reinterpret_cast<const float4*>(w1base + (ci * 4 + 3) * 256);
            const float* yb = ybase + ci * 124;
            float4 row4[16];
#pragma unroll
            for (int j = 0; j < 16; ++j)
                row4[j] = *reinterpret_cast<const float4*>(yb + 4 * j);
#pragma unroll
            for (int u = 0; u < 15; ++u) {
                acc0[u] += wA0.x * row4[u].x + wA0.y * row4[u].y
                         + wA0.z * row4[u].z + wA0.w * row4[u].w
                         + wB0.x * row4[u + 1].x + wB0.y * row4[u + 1].y
                         + wB0.z * row4[u + 1].z + wB0.w * row4[u + 1].w;
                acc1[u] += wA1.x * row4[u].x + wA1.y * row4[u].y
                         + wA1.z * row4[u].z + wA1.w * row4[u].w
                         + wB1.x * row4[u + 1].x + wB1.y * row4[u + 1].y
                         + wB1.z * row4[u + 1].z + wB1.w * row4[u + 1].w;
            }
        }
        const int b = bbase + bi;
        float* yo0 = y1g + ((size_t)b * 128 + cg) * 32 + t0;
        float* yo1 = y1g + ((size_t)b * 128 + cg + 64) * 32 + t0;
#pragma unroll
        for (int u = 0; u < 15; ++u) {
            yo0[u] = elu1(acc0[u]);
            yo1[u] = elu1(acc1[u]);
        }
    }
}

// ================= convB v6: wave=batch, 4 channels/thread ===================
// 128 thr = 2 waves; wave bi owns batch bbase+bi. Lane owns c = 4*lane..+3.
// Per ci: 8 wave-uniform row loads (scalar path, proven) feed 220 FMA/lane;
// weights are 12 dense per-lane float4 (W2c layout). acc[4][6]=24 VGPR.
__global__ __launch_bounds__(128, 2)
void convB_kernel(const float* __restrict__ state_in,
                  const float* __restrict__ b2, const float* __restrict__ b3,
                  const float* __restrict__ W2c, const float* __restrict__ W3c,
                  const float* __restrict__ y1g,
                  float* __restrict__ out, float* __restrict__ r_ws) {
    __shared__ __align__(16) float y2s[2 * 256 * 6];  // 12KB

    const int tid = threadIdx.x;
    const int bi = tid >> 6;       // wave = batch
    const int lane = tid & 63;
    const int c0 = lane * 4;
    const int b = blockIdx.x * 2 + bi;

    // ---- conv2 (128->256, k=10, s=5) + ELU ----
    {
        float acc[4][6];
        float4 bv = *reinterpret_cast<const float4*>(b2 + c0);
        const float be[4] = {bv.x, bv.y, bv.z, bv.w};
#pragma unroll
        for (int cc = 0; cc < 4; ++cc)
#pragma unroll
            for (int t = 0; t < 6; ++t) acc[cc][t] = be[cc];
        const float* w2base = W2c + c0 * 4;       // + (ci*3+jq)*1024 + cc*4
        const float* yb = y1g + (size_t)b * 4096;  // this batch's y1 (128x32)
        for (int ci = 0; ci < 128; ++ci) {
            float row[32];
#pragma unroll
            for (int k4 = 0; k4 < 8; ++k4) {
                float4 v = *reinterpret_cast<const float4*>(yb + ci * 32 + k4 * 4);
                row[k4 * 4] = v.x; row[k4 * 4 + 1] = v.y;
                row[k4 * 4 + 2] = v.z; row[k4 * 4 + 3] = v.w;
            }
            float4 wq0[4], wq1[4], wq2[4];
#pragma unroll
            for (int cc = 0; cc < 4; ++cc) {
                wq0[cc] = *reinterpret_cast<const float4*>(
                    w2base + (ci * 3 + 0) * 1024 + cc * 4);
                wq1[cc] = *reinterpret_cast<const float4*>(
                    w2base + (ci * 3 + 1) * 1024 + cc * 4);
                wq2[cc] = *reinterpret_cast<const float4*>(
                    w2base + (ci * 3 + 2) * 1024 + cc * 4);
            }
#pragma unroll
            for (int cc = 0; cc < 4; ++cc) {
                const float w[10] = {wq0[cc].x, wq0[cc].y, wq0[cc].z, wq0[cc].w,
                                     wq1[cc].x, wq1[cc].y, wq1[cc].z, wq1[cc].w,
                                     wq2[cc].x, wq2[cc].y};
                acc[cc][0] += w[5] * row[0] + w[6] * row[1] + w[7] * row[2]
                            + w[8] * row[3] + w[9] * row[4];
#pragma unroll
                for (int t = 1; t < 6; ++t) {
                    const int q0 = 5 * t - 5;
                    float s = 0.f;
#pragma unroll
                    for (int j = 0; j < 10; ++j) s += w[j] * row[q0 + j];
                    acc[cc][t] += s;
                }
            }
        }
#pragma unroll
        for (int cc = 0; cc < 4; ++cc)
#pragma unroll
            for (int t = 0; t < 6; ++t)
                y2s[(bi * 256 + c0 + cc) * 6 + t] = elu1(acc[cc][t]);
    }
    __syncthreads();
    // ---- conv3 (256->256): taps 6..11 only; no ELU ----
    {
        float acc3[4];
        float4 bv = *reinterpret_cast<const float4*>(b3 + c0);
        acc3[0] = bv.x; acc3[1] = bv.y; acc3[2] = bv.z; acc3[3] = bv.w;
        const float* w3base = W3c + c0 * 2;  // + (ci*3+jq)*512 + cc*2
        const float* y2b = y2s + bi * 1536;
        for (int ci = 0; ci < 256; ++ci) {
            const float* yr = y2b + ci * 6;  // wave-uniform broadcast
            float2 a = *reinterpret_cast<const float2*>(yr);
            float2 d = *reinterpret_cast<const float2*>(yr + 2);
            float2 e = *reinterpret_cast<const float2*>(yr + 4);
#pragma unroll
            for (int cc = 0; cc < 4; ++cc) {
                float2 w01 = *reinterpret_cast<const float2*>(
                    w3base + (ci * 3 + 0) * 512 + cc * 2);
                float2 w23 = *reinterpret_cast<const float2*>(
                    w3base + (ci * 3 + 1) * 512 + cc * 2);
                float2 w45 = *reinterpret_cast<const float2*>(
                    w3base + (ci * 3 + 2) * 512 + cc * 2);
                acc3[cc] += w01.x * a.x + w01.y * a.y + w23.x * d.x + w23.y * d.y
                          + w45.x * e.x + w45.y * e.y;
            }
        }
        float4 y3; y3.x = acc3[0]; y3.y = acc3[1]; y3.z = acc3[2]; y3.w = acc3[3];
        *reinterpret_cast<float4*>(r_ws + b * 256 + c0) = y3;
#pragma unroll
        for (int cc = 0; cc < 4; ++cc) {
            float4 si = *reinterpret_cast<const float4*>(
                state_in + b * 1024 + (c0 + cc) * 4);
            float4 o; o.x = si.y; o.y = si.z; o.z = si.w; o.w = acc3[cc];
            *reinterpret_cast<float4*>(out + 65536 + b * 1024 + (c0 + cc) * 4) = o;
        }
    }
}

// ---------------- RVQ v6: register-direct codebook (r10 proven) --------------
__device__ __forceinline__ unsigned long long distkey(float d, int k) {
    unsigned u = __float_as_uint(d);
    u = (u & 0x80000000u) ? ~u : (u | 0x80000000u);  // monotonic float->uint
    return ((unsigned long long)u << 32) | (unsigned)k;  // low idx wins ties (np argmin)
}

__global__ __launch_bounds__(256)
void rvq_kernel(const float* __restrict__ cb, const float* __restrict__ cbT,
                const float* __restrict__ cnorm, const float* __restrict__ r_ws,
                float* __restrict__ out) {
    __shared__ __align__(16) float rs[16 * 256];  // 16 KB residuals
    __shared__ unsigned long long part_sh[2][16];
    __shared__ int idx_sh[16];

    const int tid = threadIdx.x;
    const int lane = tid & 63;
    const int wid = tid >> 6;
    const int bg = wid >> 1;
    const int kg = wid & 1;
    const int b0 = blockIdx.x * 16;
    const int kb = kg * 512 + 4 * lane;

    for (int it = 0; it < 4; ++it) {
        int o = (it * 256 + tid) * 4;
        *reinterpret_cast<float4*>(rs + o) =
            *reinterpret_cast<const float4*>(r_ws + b0 * 256 + o);
    }
    __syncthreads();

    for (int q = 0; q < 8; ++q) {
        float acc[8][8];
#pragma unroll
        for (int i = 0; i < 8; ++i)
#pragma unroll
            for (int j = 0; j < 8; ++j) acc[i][j] = 0.f;

        for (int ds = 0; ds < 32; ++ds) {
            const float* sb = cbT + (size_t)(q * 32 + ds) * 8192;
#pragma unroll
            for (int dp = 0; dp < 2; ++dp) {
                float4 cv0[4], cv1[4];
#pragma unroll
                for (int dd = 0; dd < 4; ++dd) {
                    const int dl = dp * 4 + dd;
                    cv0[dd] = *reinterpret_cast<const float4*>(sb + dl * 1024 + kb);
                    cv1[dd] = *reinterpret_cast<const float4*>(sb + dl * 1024 + kb + 256);
                }
                float rr[8][4];
#pragma unroll
                for (int i = 0; i < 8; ++i) {
                    float4 t = *reinterpret_cast<const float4*>(
                        rs + (bg * 8 + i) * 256 + ds * 8 + dp * 4);
                    rr[i][0] = t.x; rr[i][1] = t.y; rr[i][2] = t.z; rr[i][3] = t.w;
                }
#pragma unroll
                for (int dd = 0; dd < 4; ++dd) {
#pragma unroll
                    for (int i = 0; i < 8; ++i) {
                        const float r = rr[i][dd];
                        acc[i][0] += r * cv0[dd].x; acc[i][1] += r * cv0[dd].y;
                        acc[i][2] += r * cv0[dd].z; acc[i][3] += r * cv0[dd].w;
                        acc[i][4] += r * cv1[dd].x; acc[i][5] += r * cv1[dd].y;
                        acc[i][6] += r * cv1[dd].z; acc[i][7] += r * cv1[dd].w;
                    }
                }
            }
        }
        {
            float4 cn0 = *reinterpret_cast<const float4*>(cnorm + q * 1024 + kb);
            float4 cn1 = *reinterpret_cast<const float4*>(cnorm + q * 1024 + kb + 256);
            float c0e[4] = {cn0.x, cn0.y, cn0.z, cn0.w};
            float c1e[4] = {cn1.x, cn1.y, cn1.z, cn1.w};
#pragma unroll
            for (int i = 0; i < 8; ++i) {
                unsigned long long k = 0xFFFFFFFFFFFFFFFFull;
#pragma unroll
                for (int e = 0; e < 4; ++e) {
                    unsigned long long ka = distkey(c0e[e] - 2.f * acc[i][e], kb + e);
                    unsigned long long kc = distkey(c1e[e] - 2.f * acc[i][4 + e],
                                                    kb + 256 + e);
                    if (ka < k) k = ka;
                    if (kc < k) k = kc;
                }
                for (int off = 32; off >= 1; off >>= 1) {
                    unsigned long long o = __shfl_xor(k, off, 64);
                    if (o < k) k = o;
                }
                if (lane == 0) part_sh[kg][bg * 8 + i] = k;
            }
        }
        __syncthreads();
        if (tid < 16) {
            unsigned long long ka = part_sh[0][tid];
            unsigned long long kc = part_sh[1][tid];
            if (kc < ka) ka = kc;
            const int idx = (int)(ka & 0xFFFFFFFFu);
            idx_sh[tid] = idx;
            out[(b0 + tid) * 8 + q] = (float)idx;
        }
        __syncthreads();
        for (int it = 0; it < 16; ++it) {
            const int idx = idx_sh[it];
            rs[it * 256 + tid] -= cb[((size_t)(q * 1024 + idx)) * 256 + tid];
        }
        __syncthreads();
    }
}

extern "C" void kernel_launch(void* const* d_in, const int* in_sizes, int n_in,
                              void* d_out, int out_size, void* d_ws, size_t ws_size,
                              hipStream_t stream) {
    const float* audio = (const float*)d_in[0];
    const float* state = (const float*)d_in[1];
    const float* W0 = (const float*)d_in[2];
    const float* b0 = (const float*)d_in[3];
    const float* W1 = (const float*)d_in[4];
    const float* b1 = (const float*)d_in[5];
    const float* W2 = (const float*)d_in[6];
    const float* b2 = (const float*)d_in[7];
    const float* W3 = (const float*)d_in[8];
    const float* b3 = (const float*)d_in[9];
    const float* cbk = (const float*)d_in[10];
    float* out = (float*)d_out;

    float* cnorm_ws = (float*)d_ws;            // 8192
    float* r_ws = cnorm_ws + 8192;             // 2097152
    float* W1c = r_ws + 2097152;               // 65536
    float* W2c = W1c + 65536;                  // 393216
    float* W3c = W2c + 393216;                 // 393216
    float* y1g = W3c + 393216;                 // 33554432
    float* cbT = y1g + 33554432;               // 2097152
    // total ~154 MB; ws>=196MB proven in r7

    cnorm_kernel<<<32, 256, 0, stream>>>(cbk, cnorm_ws);
    cbtrans_kernel<<<2048, 256, 0, stream>>>(cbk, cbT);
    wtrans_kernel<<<1216, 256, 0, stream>>>(W1, W2, W3, W1c, W2c, W3c);
    convA_kernel<<<4096, 256, 0, stream>>>(audio, W0, b0, W1c, b1, y1g);
    convB_kernel<<<4096, 128, 0, stream>>>(state, b2, b3, W2c, W3c, y1g,
                                           out, r_ws);
    rvq_kernel<<<512, 256, 0, stream>>>(cbk, cbT, cnorm_ws, r_ws, out);
}

// Round 20
// 1763.774 us; speedup vs baseline: 1.3782x; 1.3782x over previous
//
#include <hip/hip_runtime.h>
#include <hip/hip_bf16.h>

#define GB 2  // batch elems per convB block

__device__ __forceinline__ float elu1(float v) { return v > 0.f ? v : expm1f(v); }

// ---------------- fused prep: cbtrans (blocks 0..2047), wtrans (2048..3263),
//                  cnorm (3264..3295) ----------------
__global__ void prep_kernel(const float* __restrict__ cb, const float* __restrict__ W1,
                            const float* __restrict__ W2, const float* __restrict__ W3,
                            float* __restrict__ cbT, float* __restrict__ W1c,
                            float* __restrict__ W2c, float* __restrict__ W3c,
                            float* __restrict__ cnorm) {
    const int blk = blockIdx.x;
    const int tloc = threadIdx.x;
    if (blk < 2048) {  // ---- cbtrans: 524288 float4 units ----
        int t = blk * 256 + tloc;
        int o = t * 4;
        const int s = o >> 13;
        const int r = o & 8191;
        const int dl = r >> 10;
        const int k = r & 1023;
        const int q = s >> 5;
        const int d = (s & 31) * 8 + dl;
        const float* src = cb + ((size_t)(q * 1024 + k)) * 256 + d;
        float4 v;
        v.x = src[0 * 256]; v.y = src[1 * 256]; v.z = src[2 * 256]; v.w = src[3 * 256];
        *reinterpret_cast<float4*>(cbT + o) = v;
        return;
    }
    if (blk < 3264) {  // ---- wtrans ----
        int g = (blk - 2048) * 256 + tloc;
        if (g < 16384) {  // W1c, float4 units
            int ci = g >> 8, io = (g >> 6) & 3, cg = g & 63;
            int c = cg + (io >> 1) * 64;
            const float* src = W1 + c * 512 + ci * 8 + (io & 1) * 4;
            *reinterpret_cast<float4*>(W1c + g * 4) =
                *reinterpret_cast<const float4*>(src);
        }
        int g2 = g - 16384;
        if (g2 >= 0 && g2 < 98304) {  // W2c, float4 units
            int ci = g2 / 768, rem = g2 % 768;
            int jq = rem >> 8, c = rem & 255;
            float v[4];
#pragma unroll
            for (int e = 0; e < 4; ++e) {
                int j = jq * 4 + e;
                v[e] = (j < 10) ? W2[c * 1280 + ci * 10 + j] : 0.f;
            }
            float4 o; o.x = v[0]; o.y = v[1]; o.z = v[2]; o.w = v[3];
            *reinterpret_cast<float4*>(W2c + g2 * 4) = o;
        }
        int g3 = g - 16384 - 98304;
        if (g3 >= 0 && g3 < 196608) {  // W3c, float2 units
            int ci = g3 / 768, rem = g3 % 768;
            int jq = rem >> 8, c = rem & 255;
            const float* src = W3 + c * 3072 + ci * 12 + 6 + jq * 2;
            W3c[g3 * 2] = src[0];
            W3c[g3 * 2 + 1] = src[1];
        }
        return;
    }
    {  // ---- cnorm: 8192 codes ----
        int g = (blk - 3264) * 256 + tloc;
        const float* p = cb + (size_t)g * 256;
        float s = 0.f;
        for (int d = 0; d < 256; d += 4) {
            float4 v = *reinterpret_cast<const float4*>(p + d);
            s += v.x * v.x + v.y * v.y + v.z * v.z + v.w * v.w;
        }
        cnorm[g] = s;
    }
}

// ================= convA v3 (r16/r17 proven): 2 batch/block, 2 ch/thread =====
__global__ __launch_bounds__(256, 2)
void convA_kernel(const float* __restrict__ audio,
                  const float* __restrict__ W0, const float* __restrict__ b0,
                  const float* __restrict__ W1c, const float* __restrict__ b1,
                  float* __restrict__ y1g) {
    __shared__ __align__(16) float xs[244];
    __shared__ __align__(16) float y0s[2 * 64 * 124];  // 62KB, 4 left pad cols

    const int tid = threadIdx.x;
    const int bbase = blockIdx.x * 2;

    if (tid < 128) {
        const int bz = tid >> 6, ciz = tid & 63;
        float* p = y0s + (bz * 64 + ciz) * 124;
        p[0] = 0.f; p[1] = 0.f; p[2] = 0.f; p[3] = 0.f;
    }

    for (int bi2 = 0; bi2 < 2; ++bi2) {
        __syncthreads();
        if (tid < 242) xs[tid] = (tid < 2) ? 0.f : audio[(bbase + bi2) * 240 + tid - 2];
        __syncthreads();
        const int ci = tid >> 2, tg = tid & 3;
        float4 w = *reinterpret_cast<const float4*>(W0 + ci * 4);
        float bias = b0[ci];
        for (int t = tg; t < 120; t += 4) {
            float v = bias + w.x * xs[2 * t] + w.y * xs[2 * t + 1]
                           + w.z * xs[2 * t + 2] + w.w * xs[2 * t + 3];
            y0s[(bi2 * 64 + ci) * 124 + 4 + t] = elu1(v);
        }
    }
    __syncthreads();
    {
        const int bi = tid >> 7;
        const int half = (tid >> 6) & 1;
        const int cg = tid & 63;
        const int t0 = 15 * half;
        float acc0[15], acc1[15];
        const float bias0 = b1[cg], bias1 = b1[cg + 64];
#pragma unroll
        for (int u = 0; u < 15; ++u) { acc0[u] = bias0; acc1[u] = bias1; }
        const float* w1base = W1c + cg * 4;
        const float* ybase = y0s + bi * 64 * 124 + 4 * t0;
        for (int ci = 0; ci < 64; ++ci) {
            float4 wA0 = *reinterpret_cast<const float4*>(w1base + (ci * 4 + 0) * 256);
            float4 wB0 = *reinterpret_cast<const float4*>(w1base + (ci * 4 + 1) * 256);
            float4 wA1 = *reinterpret_cast<const float4*>(w1base + (ci * 4 + 2) * 256);
            float4 wB1 = *reinterpret_cast<const float4*>(w1base + (ci * 4 + 3) * 256);
            const float* yb = ybase + ci * 124;
            float4 row4[16];
#pragma unroll
            for (int j = 0; j < 16; ++j)
                row4[j] = *reinterpret_cast<const float4*>(yb + 4 * j);
#pragma unroll
            for (int u = 0; u < 15; ++u) {
                acc0[u] += wA0.x * row4[u].x + wA0.y * row4[u].y
                         + wA0.z * row4[u].z + wA0.w * row4[u].w
                         + wB0.x * row4[u + 1].x + wB0.y * row4[u + 1].y
                         + wB0.z * row4[u + 1].z + wB0.w * row4[u + 1].w;
                acc1[u] += wA1.x * row4[u].x + wA1.y * row4[u].y
                         + wA1.z * row4[u].z + wA1.w * row4[u].w
                         + wB1.x * row4[u + 1].x + wB1.y * row4[u + 1].y
                         + wB1.z * row4[u + 1].z + wB1.w * row4[u + 1].w;
            }
        }
        const int b = bbase + bi;
        float* yo0 = y1g + ((size_t)b * 128 + cg) * 32 + t0;
        float* yo1 = y1g + ((size_t)b * 128 + cg + 64) * 32 + t0;
#pragma unroll
        for (int u = 0; u < 15; ++u) {
            yo0[u] = elu1(acc0[u]);
            yo1[u] = elu1(acc1[u]);
        }
    }
}

// ================= convB v4 (r17 proven): GB=2, c=tid, y1 direct =============
__global__ __launch_bounds__(256, 2)
void convB_kernel(const float* __restrict__ state_in,
                  const float* __restrict__ b2, const float* __restrict__ b3,
                  const float* __restrict__ W2c, const float* __restrict__ W3c,
                  const float* __restrict__ y1g,
                  float* __restrict__ out, float* __restrict__ r_ws) {
    __shared__ __align__(16) float y2s[GB * 256 * 6];

    const int tid = threadIdx.x;
    const int bbase = blockIdx.x * GB;

    // ---- conv2 (128->256, k=10, s=5) + ELU ----
    {
        const int c = tid;
        float acc[GB][6];
        float bias = b2[c];
#pragma unroll
        for (int bi = 0; bi < GB; ++bi)
#pragma unroll
            for (int t = 0; t < 6; ++t) acc[bi][t] = bias;
        const float* w2base = W2c + c * 4;  // + (ci*3+jq)*1024
        for (int ci = 0; ci < 128; ++ci) {
            float4 a0 = *reinterpret_cast<const float4*>(w2base + (ci * 3 + 0) * 1024);
            float4 a1 = *reinterpret_cast<const float4*>(w2base + (ci * 3 + 1) * 1024);
            float4 a2 = *reinterpret_cast<const float4*>(w2base + (ci * 3 + 2) * 1024);
            const float w[10] = {a0.x, a0.y, a0.z, a0.w, a1.x,
                                 a1.y, a1.z, a1.w, a2.x, a2.y};
#pragma unroll
            for (int bi = 0; bi < GB; ++bi) {
                const float* yr = y1g + ((size_t)(bbase + bi) * 128 + ci) * 32;
                float row[32];
#pragma unroll
                for (int k4 = 0; k4 < 8; ++k4) {
                    float4 v = *reinterpret_cast<const float4*>(yr + k4 * 4);
                    row[k4 * 4] = v.x; row[k4 * 4 + 1] = v.y;
                    row[k4 * 4 + 2] = v.z; row[k4 * 4 + 3] = v.w;
                }
                acc[bi][0] += w[5] * row[0] + w[6] * row[1] + w[7] * row[2]
                            + w[8] * row[3] + w[9] * row[4];
#pragma unroll
                for (int t = 1; t < 6; ++t) {
                    const int q0 = 5 * t - 5;
                    float s = 0.f;
#pragma unroll
                    for (int j = 0; j < 10; ++j) s += w[j] * row[q0 + j];
                    acc[bi][t] += s;
                }
            }
        }
#pragma unroll
        for (int bi = 0; bi < GB; ++bi)
#pragma unroll
            for (int t = 0; t < 6; ++t)
                y2s[(bi * 256 + c) * 6 + t] = elu1(acc[bi][t]);
    }
    __syncthreads();
    // ---- conv3 (256->256): taps 6..11 only; no ELU ----
    {
        const int c = tid;
        float acc[GB];
        float bias = b3[c];
#pragma unroll
        for (int bi = 0; bi < GB; ++bi) acc[bi] = bias;
        const float* w3base = W3c + c * 2;  // + (ci*3+jq)*512
        for (int ci = 0; ci < 256; ++ci) {
            float2 w01 = *reinterpret_cast<const float2*>(w3base + (ci * 3 + 0) * 512);
            float2 w23 = *reinterpret_cast<const float2*>(w3base + (ci * 3 + 1) * 512);
            float2 w45 = *reinterpret_cast<const float2*>(w3base + (ci * 3 + 2) * 512);
#pragma unroll
            for (int bi = 0; bi < GB; ++bi) {
                const float* yr = y2s + (bi * 256 + ci) * 6;
                float2 a = *reinterpret_cast<const float2*>(yr);
                float2 d = *reinterpret_cast<const float2*>(yr + 2);
                float2 e = *reinterpret_cast<const float2*>(yr + 4);
                acc[bi] += w01.x * a.x + w01.y * a.y + w23.x * d.x + w23.y * d.y
                         + w45.x * e.x + w45.y * e.y;
            }
        }
#pragma unroll
        for (int bi = 0; bi < GB; ++bi) {
            const int b = bbase + bi;
            float y3 = acc[bi];
            r_ws[b * 256 + c] = y3;
            float4 si = *reinterpret_cast<const float4*>(state_in + b * 1024 + c * 4);
            float4 o; o.x = si.y; o.y = si.z; o.z = si.w; o.w = y3;
            *reinterpret_cast<float4*>(out + 65536 + b * 1024 + c * 4) = o;
        }
    }
}

// ---------------- RVQ v6: register-direct codebook (r10 proven) --------------
__device__ __forceinline__ unsigned long long distkey(float d, int k) {
    unsigned u = __float_as_uint(d);
    u = (u & 0x80000000u) ? ~u : (u | 0x80000000u);  // monotonic float->uint
    return ((unsigned long long)u << 32) | (unsigned)k;  // low idx wins ties (np argmin)
}

__global__ __launch_bounds__(256)
void rvq_kernel(const float* __restrict__ cb, const float* __restrict__ cbT,
                const float* __restrict__ cnorm, const float* __restrict__ r_ws,
                float* __restrict__ out) {
    __shared__ __align__(16) float rs[16 * 256];  // 16 KB residuals
    __shared__ unsigned long long part_sh[2][16];
    __shared__ int idx_sh[16];

    const int tid = threadIdx.x;
    const int lane = tid & 63;
    const int wid = tid >> 6;
    const int bg = wid >> 1;
    const int kg = wid & 1;
    const int b0 = blockIdx.x * 16;
    const int kb = kg * 512 + 4 * lane;

    for (int it = 0; it < 4; ++it) {
        int o = (it * 256 + tid) * 4;
        *reinterpret_cast<float4*>(rs + o) =
            *reinterpret_cast<const float4*>(r_ws + b0 * 256 + o);
    }
    __syncthreads();

    for (int q = 0; q < 8; ++q) {
        float acc[8][8];
#pragma unroll
        for (int i = 0; i < 8; ++i)
#pragma unroll
            for (int j = 0; j < 8; ++j) acc[i][j] = 0.f;

        for (int ds = 0; ds < 32; ++ds) {
            const float* sb = cbT + (size_t)(q * 32 + ds) * 8192;
#pragma unroll
            for (int dp = 0; dp < 2; ++dp) {
                float4 cv0[4], cv1[4];
#pragma unroll
                for (int dd = 0; dd < 4; ++dd) {
                    const int dl = dp * 4 + dd;
                    cv0[dd] = *reinterpret_cast<const float4*>(sb + dl * 1024 + kb);
                    cv1[dd] = *reinterpret_cast<const float4*>(sb + dl * 1024 + kb + 256);
                }
                float rr[8][4];
#pragma unroll
                for (int i = 0; i < 8; ++i) {
                    float4 t = *reinterpret_cast<const float4*>(
                        rs + (bg * 8 + i) * 256 + ds * 8 + dp * 4);
                    rr[i][0] = t.x; rr[i][1] = t.y; rr[i][2] = t.z; rr[i][3] = t.w;
                }
#pragma unroll
                for (int dd = 0; dd < 4; ++dd) {
#pragma unroll
                    for (int i = 0; i < 8; ++i) {
                        const float r = rr[i][dd];
                        acc[i][0] += r * cv0[dd].x; acc[i][1] += r * cv0[dd].y;
                        acc[i][2] += r * cv0[dd].z; acc[i][3] += r * cv0[dd].w;
                        acc[i][4] += r * cv1[dd].x; acc[i][5] += r * cv1[dd].y;
                        acc[i][6] += r * cv1[dd].z; acc[i][7] += r * cv1[dd].w;
                    }
                }
            }
        }
        {
            float4 cn0 = *reinterpret_cast<const float4*>(cnorm + q * 1024 + kb);
            float4 cn1 = *reinterpret_cast<const float4*>(cnorm + q * 1024 + kb + 256);
            float c0e[4] = {cn0.x, cn0.y, cn0.z, cn0.w};
            float c1e[4] = {cn1.x, cn1.y, cn1.z, cn1.w};
#pragma unroll
            for (int i = 0; i < 8; ++i) {
                unsigned long long k = 0xFFFFFFFFFFFFFFFFull;
#pragma unroll
                for (int e = 0; e < 4; ++e) {
                    unsigned long long ka = distkey(c0e[e] - 2.f * acc[i][e], kb + e);
                    unsigned long long kc = distkey(c1e[e] - 2.f * acc[i][4 + e],
                                                    kb + 256 + e);
                    if (ka < k) k = ka;
                    if (kc < k) k = kc;
                }
                for (int off = 32; off >= 1; off >>= 1) {
                    unsigned long long o = __shfl_xor(k, off, 64);
                    if (o < k) k = o;
                }
                if (lane == 0) part_sh[kg][bg * 8 + i] = k;
            }
        }
        __syncthreads();
        if (tid < 16) {
            unsigned long long ka = part_sh[0][tid];
            unsigned long long kc = part_sh[1][tid];
            if (kc < ka) ka = kc;
            const int idx = (int)(ka & 0xFFFFFFFFu);
            idx_sh[tid] = idx;
            out[(b0 + tid) * 8 + q] = (float)idx;
        }
        __syncthreads();
        for (int it = 0; it < 16; ++it) {
            const int idx = idx_sh[it];
            rs[it * 256 + tid] -= cb[((size_t)(q * 1024 + idx)) * 256 + tid];
        }
        __syncthreads();
    }
}

extern "C" void kernel_launch(void* const* d_in, const int* in_sizes, int n_in,
                              void* d_out, int out_size, void* d_ws, size_t ws_size,
                              hipStream_t stream) {
    const float* audio = (const float*)d_in[0];
    const float* state = (const float*)d_in[1];
    const float* W0 = (const float*)d_in[2];
    const float* b0 = (const float*)d_in[3];
    const float* W1 = (const float*)d_in[4];
    const float* b1 = (const float*)d_in[5];
    const float* W2 = (const float*)d_in[6];
    const float* b2 = (const float*)d_in[7];
    const float* W3 = (const float*)d_in[8];
    const float* b3 = (const float*)d_in[9];
    const float* cbk = (const float*)d_in[10];
    float* out = (float*)d_out;

    float* cnorm_ws = (float*)d_ws;            // 8192
    float* r_ws = cnorm_ws + 8192;             // 2097152
    float* W1c = r_ws + 2097152;               // 65536
    float* W2c = W1c + 65536;                  // 393216
    float* W3c = W2c + 393216;                 // 393216
    float* y1g = W3c + 393216;                 // 33554432
    float* cbT = y1g + 33554432;               // 2097152
    // total ~154 MB; ws>=196MB proven in r7

    prep_kernel<<<3296, 256, 0, stream>>>(cbk, W1, W2, W3, cbT, W1c, W2c, W3c,
                                          cnorm_ws);
    convA_kernel<<<4096, 256, 0, stream>>>(audio, W0, b0, W1c, b1, y1g);
    convB_kernel<<<8192 / GB, 256, 0, stream>>>(state, b2, b3, W2c, W3c, y1g,
                                                out, r_ws);
    rvq_kernel<<<512, 256, 0, stream>>>(cbk, cbT, cnorm_ws, r_ws, out);
}